// Round 7
// baseline (799.151 us; speedup 1.0000x reference)
//
#include <hip/hip_runtime.h>
#include <hip/hip_bf16.h>

// MambaSpatial: B=32, C_IN=D=96, H=W=48, L=2304, K=2, N=16, R=6.
// R5/R6: universal scan path: decay_n = P^(n+1) * poly3(e_n*dt),
// P = exp(-dt) = 1/(1+e^a) (exact sigmoid identity),
// e_n = (n+1)-exp(A_log_n) precomputed (|e_n*dt|<=0.06 -> poly3 err ~4e-7).
// Exact for both bf16 and f32 A_logs; kills 16 exp2/step.
// scan3ln: single y-tile via LDS atomicAdd (2 commutative adds/cell, exact)
// -> LDS 35.3->22.9KB -> 6 blocks/CU. gatherd+tr_dl fused (saves 56MB traffic).

typedef __hip_bfloat16 bf16;
__device__ __forceinline__ float b2f(bf16 v) { return __bfloat162float(v); }
__device__ __forceinline__ float ldu(const void* p, int i, bool f32) {
  if (f32) return ((const float*)p)[i];
  return b2f(((const bf16*)p)[i]);
}

#define LL 2304
#define NSEG 72          // 32-step segments

// ---- wbuf offsets (floats) ----
#define W_INT  0        // in_proj_w transposed [c][d] 9216
#define B_IN   9216
#define W_C2D  9312
#define B_C2D  10176
#define W_LOC  10272
#define B_LOC  11136
#define BN_G   11232
#define BN_B   11328
#define W_XPT  11424    // x_proj_w transposed [d][80]
#define W_DT   19104    // dt_projs_w [k][d][6]
#define B_DT   20256
#define A2OF   20448    // -exp(A_logs)*log2(e) [k][d][16] (scan2 stitch)
#define DSOF   23520
#define LN_G   23712
#define LN_B   23808
#define W_OUTT 23904    // out_proj_w transposed [d][c]
#define B_OUT  33120
#define W_EC   33280    // (n+1) - exp(A_logs)  [k][d][16]  (poly correction)
#define WBUF_N 36352ul

// ---- workspace layout (float offsets) ----
#define O_WBUF  0ul
#define O_XFEAT 36352ul        // 7,077,888 ; reused: hend ; then ymdm
#define O_XCONV 7114240ul      // 7,077,888
#define O_SIM   14192128ul     // 73,728
#define O_SIDX  14265856ul     // 73,728 (int)
#define O_XST   14339584ul     // sorted l-major [b][l][d] ; reused: lcbuf
#define O_XSTD  21417472ul     // sorted d-major [b][d][l] ; reused: hstart
#define O_RBUF  28495360ul     // [b][k][l][8]
#define O_BC    29675008ul     // [b][k][l][32]
#define O_DSUM  34393600ul     // [b][k][d][72] 442,368
#define O_YMLM  34835968ul     // [b][p][96] 7,077,888
#define O_STATS 41913856ul     // 192
#define O_SCSH  41914112ul     // 192
#define O_FLAG  41914304ul     // 64 (dtype flag)
#define O_END   41914368ul     // ~167.7 MB

// ---------------- dtype detect ----------------
__global__ void k_detect(const void* x, float* flag) {
  int i = threadIdx.x;
  bool bad = false;
  const bf16* xb = (const bf16*)x;
#pragma unroll
  for (int r = 0; r < 4; ++r) {
    float v = b2f(xb[r * 64 + i]);
    if (!(fabsf(v) <= 1e4f)) bad = true;
  }
  bool any = __any(bad);
  if (i == 0) flag[0] = any ? 1.f : 0.f;
}

// ---------------- prep ----------------
__global__ void k_prep(const void* ipw, const void* ipb, const void* c2w, const void* c2b,
                       const void* lw, const void* lb, const void* bng, const void* bnb,
                       const void* xpw, const void* dtw, const void* dtb, const void* alog,
                       const void* dss, const void* ng, const void* nb, const void* opw,
                       const void* opb, float* wb, const float* flag) {
  bool f = flag[0] > 0.5f;
  int i = blockIdx.x * 256 + threadIdx.x;
  if (i < 9216) {
    int r = i / 96, c = i % 96;
    wb[W_INT + c * 96 + r] = ldu(ipw, i, f);
    wb[W_OUTT + c * 96 + r] = ldu(opw, i, f);
  }
  if (i < 96) {
    wb[B_IN + i] = ldu(ipb, i, f); wb[B_C2D + i] = ldu(c2b, i, f); wb[B_LOC + i] = ldu(lb, i, f);
    wb[BN_G + i] = ldu(bng, i, f); wb[BN_B + i] = ldu(bnb, i, f); wb[LN_G + i] = ldu(ng, i, f);
    wb[LN_B + i] = ldu(nb, i, f); wb[B_OUT + i] = ldu(opb, i, f);
  }
  if (i < 864) { wb[W_C2D + i] = ldu(c2w, i, f); wb[W_LOC + i] = ldu(lw, i, f); }
  if (i < 7296) {
    int k = i / 3648, c = (i / 96) % 38, d = i % 96;
    wb[W_XPT + d * 80 + k * 38 + c] = ldu(xpw, i, f);
  }
  if (i < 1152) wb[W_DT + i] = ldu(dtw, i, f);
  if (i < 192) { wb[B_DT + i] = ldu(dtb, i, f); wb[DSOF + i] = ldu(dss, i, f); }
  if (i < 3072) {
    float av = expf(ldu(alog, i, f));
    wb[A2OF + i] = -av * 1.4426950408889634f;
    wb[W_EC + i] = (float)((i % 16) + 1) - av;
  }
}

// ---------------- in_proj (acc-major, d-split x2, 128 thr) ----------------
__global__ __launch_bounds__(128, 4)
void k_inproj(const void* __restrict__ x, const float* __restrict__ wb,
              float* __restrict__ xfeat, const float* __restrict__ flag) {
  int b = blockIdx.x / 36;
  int rest = blockIdx.x % 36;
  int half = rest / 18;
  int l = (rest % 18) * 128 + threadIdx.x;
  float acc[48];
#pragma unroll
  for (int j = 0; j < 48; ++j) acc[j] = wb[B_IN + half * 48 + j];
  bool f = flag[0] > 0.5f;
  if (f) {
    const float* xf = (const float*)x;
#pragma unroll 2
    for (int c = 0; c < 96; ++c) {
      float xc = xf[(b * 96 + c) * LL + l];
      const float* wr = wb + W_INT + c * 96 + half * 48;
#pragma unroll
      for (int j = 0; j < 48; ++j) acc[j] += xc * wr[j];
    }
  } else {
    const bf16* xb = (const bf16*)x;
#pragma unroll 2
    for (int c = 0; c < 96; ++c) {
      float xc = b2f(xb[(b * 96 + c) * LL + l]);
      const float* wr = wb + W_INT + c * 96 + half * 48;
#pragma unroll
      for (int j = 0; j < 48; ++j) acc[j] += xc * wr[j];
    }
  }
#pragma unroll
  for (int j = 0; j < 48; ++j) xfeat[(b * 96 + half * 48 + j) * LL + l] = acc[j];
}

// ---------------- depthwise 3x3 + bias + silu ----------------
__global__ __launch_bounds__(256, 8)
void k_conv_silu(const float* __restrict__ xfeat, const float* __restrict__ wb,
                 float* __restrict__ xconv) {
  int t = blockIdx.x * 256 + threadIdx.x;
  int l = t % LL; int d = (t / LL) % 96; int b = t / (LL * 96);
  int h = l / 48, w = l % 48;
  const float* wr = wb + W_C2D + d * 9;
  const float* src = xfeat + (b * 96 + d) * LL;
  float acc = wb[B_C2D + d];
#pragma unroll
  for (int ki = 0; ki < 3; ++ki) {
    int hh = h + ki - 1; if (hh < 0 || hh >= 48) continue;
#pragma unroll
    for (int kj = 0; kj < 3; ++kj) {
      int ww = w + kj - 1; if (ww < 0 || ww >= 48) continue;
      acc += src[hh * 48 + ww] * wr[ki * 3 + kj];
    }
  }
  xconv[t] = acc / (1.f + expf(-acc));
}

// ---------------- cosine-sim vs center pixel ----------------
__global__ __launch_bounds__(256, 8)
void k_sim(const float* __restrict__ xconv, float* __restrict__ sim) {
  int b = blockIdx.x / 9;
  int l = (blockIdx.x % 9) * 256 + threadIdx.x;
  const float* base = xconv + (size_t)b * 96 * LL;
  float dot = 0, nrm = 0, cn = 0;
  for (int d = 0; d < 96; ++d) {
    float v = base[d * LL + l];
    float c = base[d * LL + 1176];
    dot += v * c; nrm += v * v; cn += c * c;
  }
  float den = fmaxf(sqrtf(nrm), 1e-12f) * fmaxf(sqrtf(cn), 1e-12f);
  sim[b * LL + l] = dot / den;
}

// ---------------- per-batch stable argsort desc (bitonic) ----------------
__global__ void k_sort(const float* __restrict__ sim, int* __restrict__ sidx) {
  __shared__ unsigned long long key[4096];
  int b = blockIdx.x;
  for (int i = threadIdx.x; i < 4096; i += 1024) {
    unsigned long long kv = ~0ull;
    if (i < LL) {
      unsigned u = __float_as_uint(sim[b * LL + i]);
      u = (u >> 31) ? ~u : (u | 0x80000000u);
      kv = (((unsigned long long)(~u)) << 32) | (unsigned)i;
    }
    key[i] = kv;
  }
  __syncthreads();
  for (int k = 2; k <= 4096; k <<= 1)
    for (int j = k >> 1; j > 0; j >>= 1) {
      for (int i = threadIdx.x; i < 4096; i += 1024) {
        int ij = i ^ j;
        if (ij > i) {
          unsigned long long a = key[i], c = key[ij];
          bool up = ((i & k) == 0);
          if ((a > c) == up) { key[i] = c; key[ij] = a; }
        }
      }
      __syncthreads();
    }
  for (int i = threadIdx.x; i < LL; i += 1024) sidx[b * LL + i] = (int)(key[i] & 0xffffffffu);
}

// ---------------- gather + dual-layout emit: xstd[b][d][l'] and xst[b][l'][d] ----------------
__global__ __launch_bounds__(256, 4)
void k_gather_tr(const float* __restrict__ xconv, const int* __restrict__ sidx,
                 float* __restrict__ xstd, float* __restrict__ xst) {
  __shared__ float tile[64 * 97];
  __shared__ int sp[64];
  int b = blockIdx.x / 36;
  int l0 = (blockIdx.x % 36) * 64;
  if (threadIdx.x < 64) sp[threadIdx.x] = sidx[b * LL + l0 + threadIdx.x];
  __syncthreads();
#pragma unroll
  for (int it = 0; it < 24; ++it) {
    int idx = it * 256 + threadIdx.x;
    int d = idx / 64, j = idx % 64;
    tile[j * 97 + d] = xconv[((size_t)b * 96 + d) * LL + sp[j]];
  }
  __syncthreads();
#pragma unroll
  for (int it = 0; it < 24; ++it) {
    int idx = it * 256 + threadIdx.x;
    int d = idx / 64, j = idx % 64;
    xstd[((size_t)b * 96 + d) * LL + l0 + j] = tile[j * 97 + d];
  }
#pragma unroll
  for (int it = 0; it < 24; ++it) {
    int idx = it * 256 + threadIdx.x;
    int r = idx / 96, c = idx % 96;
    xst[((size_t)b * LL + l0 + r) * 96 + c] = tile[r * 97 + c];
  }
}

// ---------------- x_dbl for one direction (acc-major, 128 thr) ----------------
template <int KSEL>
__global__ __launch_bounds__(128, 4)
void k_xdbl(const float* __restrict__ xstd, const float* __restrict__ wb,
            float* __restrict__ rbuf, float* __restrict__ bc) {
  int b = blockIdx.x / 18;
  int l = (blockIdx.x % 18) * 128 + threadIdx.x;
  float acc[38];
#pragma unroll
  for (int j = 0; j < 38; ++j) acc[j] = 0.f;
#pragma unroll 2
  for (int c = 0; c < 96; ++c) {
    float xc = xstd[((size_t)b * 96 + c) * LL + l];
    const float* wr = wb + W_XPT + c * 80 + KSEL * 38;   // uniform -> s_load
#pragma unroll
    for (int j = 0; j < 38; ++j) acc[j] += xc * wr[j];
  }
  int lout = KSEL ? (LL - 1 - l) : l;
  float4* r4 = (float4*)(rbuf + ((size_t)(b * 2 + KSEL) * LL + lout) * 8);
  r4[0] = make_float4(acc[0], acc[1], acc[2], acc[3]);
  r4[1] = make_float4(acc[4], acc[5], 0.f, 0.f);
  float4* b4 = (float4*)(bc + ((size_t)(b * 2 + KSEL) * LL + lout) * 32);
#pragma unroll
  for (int i = 0; i < 8; ++i)
    b4[i] = make_float4(acc[6 + 4 * i], acc[7 + 4 * i], acc[8 + 4 * i], acc[9 + 4 * i]);
}

// per-step scalars: a -> dtv (softplus), dtx, P = exp(-dt), pw[n] = P^(n+1)
__device__ __forceinline__ void scan_coeffs(const float* rr, const float* wd, float bd,
                                            float xv, float& dtv, float& dtx, float* pw) {
  float a = bd + rr[0] * wd[0] + rr[1] * wd[1] + rr[2] * wd[2]
               + rr[3] * wd[3] + rr[4] * wd[4] + rr[5] * wd[5];
  float ea = expf(a);
  dtv = (a > 20.f) ? a : log1pf(ea);
  dtx = dtv * xv;
  float P = 1.f / (1.f + ea);
  pw[0] = P;
#pragma unroll
  for (int n = 1; n < 16; ++n) pw[n] = pw[n - 1] * P;
}
// decay correction: P^(n+1)*poly3(ec_n*dtv) with poly3(t)=1+t+t^2/2+t^3/6
__device__ __forceinline__ float corr3(float ec, float dtv) {
  float tt = ec * dtv;
  float u = fmaf(tt, 0.16666667f, 0.5f);
  float v = fmaf(tt, u, 1.f);
  return fmaf(tt, v, 1.f);
}

// ---------------- scan pass 1: 32-step segments, LDS-staged bc/rr ----------------
__global__ __launch_bounds__(192, 5)
void k_scan1(const float* __restrict__ rbuf, const float* __restrict__ bc,
             const float* __restrict__ xst, const float* __restrict__ wb,
             float* __restrict__ dsum, float* __restrict__ hend) {
  __shared__ float sbc[2][1024];
  __shared__ float srr[2][256];
  int sub = threadIdx.x / 96;
  int tid = threadIdx.x - sub * 96;
  int unit = blockIdx.x * 2 + sub;             // b*144 + k*72 + s
  int s = unit % 72; int k = (unit / 72) % 2; int b = unit / 144;
  int lbase = (b * 2 + k) * LL + s * 32;
  {
    const float4* bsrc = (const float4*)(bc + (size_t)lbase * 32);
    float4* bdst = (float4*)sbc[sub];
    for (int i = tid; i < 256; i += 96) bdst[i] = bsrc[i];
    const float4* rsrc = (const float4*)(rbuf + (size_t)lbase * 8);
    float4* rdst = (float4*)srr[sub];
    if (tid < 64) rdst[tid] = rsrc[tid];
  }
  __syncthreads();
  int d = tid;
  float wd[6];
#pragma unroll
  for (int j = 0; j < 6; ++j) wd[j] = wb[W_DT + (k * 96 + d) * 6 + j];
  float bd = wb[B_DT + k * 96 + d];
  float ec[16], h[16];
#pragma unroll
  for (int n = 0; n < 16; ++n) { ec[n] = wb[W_EC + (k * 96 + d) * 16 + n]; h[n] = 0.f; }
  float ds = 0.f;
  long long lk0 = k ? (LL - 1 - s * 32) : (s * 32);
  long long stp = k ? -96 : 96;
  const float* xp = xst + (size_t)b * LL * 96 + lk0 * 96 + d;
#pragma unroll 4
  for (int t = 0; t < 32; ++t) {
    float xv = *xp; xp += stp;
    const float* rr = &srr[sub][t * 8];
    const float* bcl = &sbc[sub][t * 32];
    float dtv, dtx, pw[16];
    scan_coeffs(rr, wd, bd, xv, dtv, dtx, pw);
    ds += dtv;
#pragma unroll
    for (int n = 0; n < 16; ++n)
      h[n] = fmaf(pw[n] * corr3(ec[n], dtv), h[n], dtx * bcl[n]);
  }
  dsum[((b * 2 + k) * 96 + d) * NSEG + s] = ds;
  float4* ho = (float4*)(hend + (((size_t)(b * 2 + k) * NSEG + s) * 96 + d) * 16);
  ho[0] = make_float4(h[0], h[1], h[2], h[3]);
  ho[1] = make_float4(h[4], h[5], h[6], h[7]);
  ho[2] = make_float4(h[8], h[9], h[10], h[11]);
  ho[3] = make_float4(h[12], h[13], h[14], h[15]);
}

// ---------------- scan pass 2: stitch 72 segments ----------------
__global__ __launch_bounds__(256, 4)
void k_scan2(const float* __restrict__ dsum, const float* __restrict__ hend,
             const float* __restrict__ wb, float* __restrict__ hstart) {
  int t = blockIdx.x * 256 + threadIdx.x;
  int n = t % 16; int d = (t / 16) % 96; int k = (t / 1536) % 2; int b = t / 3072;
  float a2 = wb[A2OF + (k * 96 + d) * 16 + n];
  float h = 0.f;
  int rowd = ((b * 2 + k) * 96 + d) * NSEG;
  for (int s = 0; s < NSEG; ++s) {
    size_t idx = (((size_t)(b * 2 + k) * NSEG + s) * 96 + d) * 16 + n;
    hstart[idx] = h;
    h = exp2f(a2 * dsum[rowd + s]) * h + hend[idx];
  }
}

// ---------------- scan3 + combine + LN (single y-tile, LDS atomic add) ----------------
__global__ __launch_bounds__(192, 5)
void k_scan3ln(const float* __restrict__ rbuf, const float* __restrict__ bc,
               const float* __restrict__ xst, const float* __restrict__ wb,
               const float* __restrict__ hstart, const int* __restrict__ sidx,
               float* __restrict__ ymlm) {
  __shared__ float yt[32 * 97];
  __shared__ float sbc[2][1024];
  __shared__ float srr[2][256];
  __shared__ float smu[32], srs[32];
  int b = blockIdx.x / NSEG;
  int u = blockIdx.x % NSEG;
  int t = threadIdx.x;
  int sub = t / 96;                      // sub==k
  int d = t - sub * 96;
  int k = sub;
  int seg = sub ? (NSEG - 1 - u) : u;
  int lbase = (b * 2 + k) * LL + seg * 32;
  for (int i = t; i < 32 * 97; i += 192) yt[i] = 0.f;
  {
    const float4* bsrc = (const float4*)(bc + (size_t)lbase * 32);
    float4* bdst = (float4*)sbc[sub];
    for (int i = d; i < 256; i += 96) bdst[i] = bsrc[i];
    const float4* rsrc = (const float4*)(rbuf + (size_t)lbase * 8);
    float4* rdst = (float4*)srr[sub];
    if (d < 64) rdst[d] = rsrc[d];
  }
  __syncthreads();
  {
    float wd[6];
#pragma unroll
    for (int j = 0; j < 6; ++j) wd[j] = wb[W_DT + (k * 96 + d) * 6 + j];
    float bd = wb[B_DT + k * 96 + d];
    float Dv = wb[DSOF + k * 96 + d];
    float ec[16], h[16];
    const float* hi = hstart + (((size_t)(b * 2 + k) * NSEG + seg) * 96 + d) * 16;
#pragma unroll
    for (int n = 0; n < 16; ++n) { ec[n] = wb[W_EC + (k * 96 + d) * 16 + n]; h[n] = hi[n]; }
    long long lk0 = k ? (LL - 1 - seg * 32) : (seg * 32);
    long long stp = k ? -96 : 96;
    const float* xp = xst + (size_t)b * LL * 96 + lk0 * 96 + d;
#pragma unroll 4
    for (int i = 0; i < 32; ++i) {
      float xv = *xp; xp += stp;
      const float* rr = &srr[sub][i * 8];
      const float* bcl = &sbc[sub][i * 32];
      float dtv, dtx, pw[16];
      scan_coeffs(rr, wd, bd, xv, dtv, dtx, pw);
      float y = 0.f;
#pragma unroll
      for (int n = 0; n < 16; ++n) {
        h[n] = fmaf(pw[n] * corr3(ec[n], dtv), h[n], dtx * bcl[n]);
        y = fmaf(h[n], bcl[16 + n], y);
      }
      int qloc = k ? (31 - i) : i;
      atomicAdd(&yt[qloc * 97 + d], y + Dv * xv);
    }
  }
  __syncthreads();
  if (t < 32) {
    float sum = 0, ss = 0;
#pragma unroll
    for (int dd = 0; dd < 96; ++dd) {
      float v = yt[t * 97 + dd];
      sum += v; ss += v * v;
    }
    float mu = sum * (1.f / 96.f);
    float var = ss * (1.f / 96.f) - mu * mu;
    smu[t] = mu;
    srs[t] = rsqrtf(var + 1e-5f);
  }
  __syncthreads();
  {
    int r = t / 6, c0 = (t % 6) * 16;
    int q = u * 32 + r;
    int p = sidx[b * LL + q];
    float mu = smu[r], rs = srs[r];
    float tmp[16];
#pragma unroll
    for (int j = 0; j < 16; ++j) {
      int dd = c0 + j;
      tmp[j] = (yt[r * 97 + dd] - mu) * rs * wb[LN_G + dd] + wb[LN_B + dd];
    }
    float4* o4 = (float4*)(ymlm + ((size_t)b * LL + p) * 96 + c0);
    o4[0] = make_float4(tmp[0], tmp[1], tmp[2], tmp[3]);
    o4[1] = make_float4(tmp[4], tmp[5], tmp[6], tmp[7]);
    o4[2] = make_float4(tmp[8], tmp[9], tmp[10], tmp[11]);
    o4[3] = make_float4(tmp[12], tmp[13], tmp[14], tmp[15]);
  }
}

// ---------------- transpose l-major -> d-major ----------------
__global__ __launch_bounds__(256, 4)
void k_tr_ld(const float* __restrict__ in, float* __restrict__ out) {
  __shared__ float tile[64 * 97];
  int b = blockIdx.x / 36;
  int l0 = (blockIdx.x % 36) * 64;
#pragma unroll
  for (int it = 0; it < 24; ++it) {
    int idx = it * 256 + threadIdx.x;
    int r = idx / 96, c = idx % 96;
    tile[r * 97 + c] = in[((size_t)b * LL + l0 + r) * 96 + c];
  }
  __syncthreads();
#pragma unroll
  for (int it = 0; it < 24; ++it) {
    int idx = it * 256 + threadIdx.x;
    int d = idx / 64, j = idx % 64;
    out[((size_t)b * 96 + d) * LL + l0 + j] = tile[j * 97 + d];
  }
}

// ---------------- local conv + bias + BN stats (fused) ----------------
__global__ __launch_bounds__(256, 8)
void k_convlc_bn(const float* __restrict__ xconv, const float* __restrict__ wb,
                 float* __restrict__ lcbuf, float* __restrict__ stats) {
  int bd = blockIdx.x;
  int b = bd / 96, d = bd % 96;
  const float* src = xconv + (size_t)(b * 96 + d) * LL;
  const float* wr = wb + W_LOC + d * 9;
  float bias = wb[B_LOC + d];
  float s1 = 0, s2 = 0;
  for (int l = threadIdx.x; l < LL; l += 256) {
    int h = l / 48, w = l % 48;
    float acc = bias;
#pragma unroll
    for (int ki = 0; ki < 3; ++ki) {
      int hh = h + ki - 1; if (hh < 0 || hh >= 48) continue;
#pragma unroll
      for (int kj = 0; kj < 3; ++kj) {
        int ww = w + kj - 1; if (ww < 0 || ww >= 48) continue;
        acc += src[hh * 48 + ww] * wr[ki * 3 + kj];
      }
    }
    lcbuf[(size_t)(b * 96 + d) * LL + l] = acc;
    s1 += acc; s2 += acc * acc;
  }
  __shared__ float r1[256], r2[256];
  r1[threadIdx.x] = s1; r2[threadIdx.x] = s2; __syncthreads();
  for (int o = 128; o > 0; o >>= 1) {
    if (threadIdx.x < o) { r1[threadIdx.x] += r1[threadIdx.x + o]; r2[threadIdx.x] += r2[threadIdx.x + o]; }
    __syncthreads();
  }
  if (threadIdx.x == 0) { atomicAdd(&stats[d], r1[0]); atomicAdd(&stats[96 + d], r2[0]); }
}

__global__ void k_bnfin(const float* __restrict__ stats, const float* __restrict__ wb,
                        float* __restrict__ scsh) {
  int d = threadIdx.x; if (d >= 96) return;
  float mean = stats[d] * (1.f / 73728.f);
  float var = stats[96 + d] * (1.f / 73728.f) - mean * mean;
  float sc = wb[BN_G + d] * rsqrtf(var + 1e-5f);
  scsh[d] = sc; scsh[96 + d] = wb[BN_B + d] - mean * sc;
}

// ---------------- final (acc-major, c-split x2, 128 thr) ----------------
__global__ __launch_bounds__(128, 4)
void k_final(const float* __restrict__ lcbuf, const float* __restrict__ ymdm,
             const float* __restrict__ wb, const float* __restrict__ scsh,
             void* __restrict__ out, const float* __restrict__ flag) {
  int b = blockIdx.x / 36;
  int rest = blockIdx.x % 36;
  int half = rest / 18;
  int l = (rest % 18) * 128 + threadIdx.x;
  float acc[48];
#pragma unroll
  for (int j = 0; j < 48; ++j) acc[j] = wb[B_OUT + half * 48 + j];
#pragma unroll 2
  for (int d = 0; d < 96; ++d) {
    float lc = lcbuf[((size_t)b * 96 + d) * LL + l] * scsh[d] + scsh[96 + d];
    float vd = lc / (1.f + expf(-lc)) + ymdm[((size_t)b * 96 + d) * LL + l];
    const float* wr = wb + W_OUTT + d * 96 + half * 48;   // uniform -> s_load
#pragma unroll
    for (int j = 0; j < 48; ++j) acc[j] += vd * wr[j];
  }
  bool f = flag[0] > 0.5f;
  if (f) {
    float* of = (float*)out;
#pragma unroll
    for (int j = 0; j < 48; ++j) of[(b * 96 + half * 48 + j) * LL + l] = acc[j];
  } else {
    bf16* ob = (bf16*)out;
#pragma unroll
    for (int j = 0; j < 48; ++j) ob[(b * 96 + half * 48 + j) * LL + l] = __float2bfloat16(acc[j]);
  }
}

extern "C" void kernel_launch(void* const* d_in, const int* in_sizes, int n_in,
                              void* d_out, int out_size, void* d_ws, size_t ws_size,
                              hipStream_t stream) {
  if (ws_size < O_END * sizeof(float)) return;
  float* ws = (float*)d_ws;
  float* wb    = ws + O_WBUF;
  float* xfeat = ws + O_XFEAT;
  float* xconv = ws + O_XCONV;
  float* sim   = ws + O_SIM;
  int*   sidx  = (int*)(ws + O_SIDX);
  float* xst   = ws + O_XST;
  float* xstd  = ws + O_XSTD;
  float* rbuf  = ws + O_RBUF;
  float* bc    = ws + O_BC;
  float* dsum  = ws + O_DSUM;
  float* ymlm  = ws + O_YMLM;
  float* stats = ws + O_STATS;
  float* scsh  = ws + O_SCSH;
  float* flag  = ws + O_FLAG;
  float* hend   = xfeat;   // xfeat dead after conv_silu
  float* hstart = xstd;    // xstd dead after xdbl
  float* ymdm   = xfeat;   // hend dead after scan2
  float* lcbuf  = xst;     // xst dead after scan3ln

  (void)hipMemsetAsync(stats, 0, 192 * sizeof(float), stream);
  k_detect<<<1, 64, 0, stream>>>(d_in[0], flag);
  k_prep<<<36, 256, 0, stream>>>(
      d_in[1], d_in[2], d_in[5], d_in[6], d_in[7], d_in[8], d_in[9], d_in[10],
      d_in[11], d_in[12], d_in[13], d_in[14], d_in[15], d_in[16], d_in[17], d_in[18],
      d_in[19], wb, flag);
  k_inproj<<<1152, 128, 0, stream>>>(d_in[0], wb, xfeat, flag);
  k_conv_silu<<<27648, 256, 0, stream>>>(xfeat, wb, xconv);
  k_sim<<<288, 256, 0, stream>>>(xconv, sim);
  k_sort<<<32, 1024, 0, stream>>>(sim, sidx);
  k_gather_tr<<<1152, 256, 0, stream>>>(xconv, sidx, xstd, xst);
  k_xdbl<0><<<576, 128, 0, stream>>>(xstd, wb, rbuf, bc);
  k_xdbl<1><<<576, 128, 0, stream>>>(xstd, wb, rbuf, bc);
  k_scan1<<<2304, 192, 0, stream>>>(rbuf, bc, xst, wb, dsum, hend);
  k_scan2<<<384, 256, 0, stream>>>(dsum, hend, wb, hstart);
  k_scan3ln<<<2304, 192, 0, stream>>>(rbuf, bc, xst, wb, hstart, sidx, ymlm);
  k_tr_ld<<<1152, 256, 0, stream>>>(ymlm, ymdm);
  k_convlc_bn<<<3072, 256, 0, stream>>>(xconv, wb, lcbuf, stats);
  k_bnfin<<<1, 96, 0, stream>>>(stats, wb, scsh);
  k_final<<<1152, 128, 0, stream>>>(lcbuf, ymdm, wb, scsh, d_out, flag);
}

// Round 8
// 708.630 us; speedup vs baseline: 1.1277x; 1.1277x over previous
//
#include <hip/hip_runtime.h>
#include <hip/hip_bf16.h>

// MambaSpatial: B=32, C_IN=D=96, H=W=48, L=2304, K=2, N=16, R=6.
// R7 lesson: __launch_bounds__(192,5) cut the VGPR cap -> h[16]/pw[16]
// spilled to scratch (VGPR=48, 526MB scratch traffic, scan1 195us).
// Now (192,4) + incremental P-power chain (no pw array). Both scan kernels
// pair k0-seg u with k1-seg NSEG-1-u (same physical q-range) and stage the
// 32x96 x-tile in LDS -> zero global loads inside the serial loop.
// Universal decay path: decay_n = P^(n+1)*poly3(ec_n*dt), P=1/(1+e^a).

typedef __hip_bfloat16 bf16;
__device__ __forceinline__ float b2f(bf16 v) { return __bfloat162float(v); }
__device__ __forceinline__ float ldu(const void* p, int i, bool f32) {
  if (f32) return ((const float*)p)[i];
  return b2f(((const bf16*)p)[i]);
}

#define LL 2304
#define NSEG 72          // 32-step segments

// ---- wbuf offsets (floats) ----
#define W_INT  0        // in_proj_w transposed [c][d] 9216
#define B_IN   9216
#define W_C2D  9312
#define B_C2D  10176
#define W_LOC  10272
#define B_LOC  11136
#define BN_G   11232
#define BN_B   11328
#define W_XPT  11424    // x_proj_w transposed [d][80]
#define W_DT   19104    // dt_projs_w [k][d][6]
#define B_DT   20256
#define A2OF   20448    // -exp(A_logs)*log2(e) [k][d][16] (scan2 stitch)
#define DSOF   23520
#define LN_G   23712
#define LN_B   23808
#define W_OUTT 23904    // out_proj_w transposed [d][c]
#define B_OUT  33120
#define W_EC   33280    // (n+1) - exp(A_logs)  [k][d][16]  (poly correction)
#define WBUF_N 36352ul

// ---- workspace layout (float offsets) ----
#define O_WBUF  0ul
#define O_XFEAT 36352ul        // 7,077,888 ; reused: hend ; then ymdm
#define O_XCONV 7114240ul      // 7,077,888
#define O_SIM   14192128ul     // 73,728
#define O_SIDX  14265856ul     // 73,728 (int)
#define O_XST   14339584ul     // sorted l-major [b][l][d] ; reused: lcbuf
#define O_XSTD  21417472ul     // sorted d-major [b][d][l] ; reused: hstart
#define O_RBUF  28495360ul     // [b][k][l][8]
#define O_BC    29675008ul     // [b][k][l][32]
#define O_DSUM  34393600ul     // [b][k][d][72] 442,368
#define O_YMLM  34835968ul     // [b][p][96] 7,077,888
#define O_STATS 41913856ul     // 192
#define O_SCSH  41914112ul     // 192
#define O_FLAG  41914304ul     // 64 (dtype flag)
#define O_END   41914368ul     // ~167.7 MB

// ---------------- dtype detect ----------------
__global__ void k_detect(const void* x, float* flag) {
  int i = threadIdx.x;
  bool bad = false;
  const bf16* xb = (const bf16*)x;
#pragma unroll
  for (int r = 0; r < 4; ++r) {
    float v = b2f(xb[r * 64 + i]);
    if (!(fabsf(v) <= 1e4f)) bad = true;
  }
  bool any = __any(bad);
  if (i == 0) flag[0] = any ? 1.f : 0.f;
}

// ---------------- prep ----------------
__global__ void k_prep(const void* ipw, const void* ipb, const void* c2w, const void* c2b,
                       const void* lw, const void* lb, const void* bng, const void* bnb,
                       const void* xpw, const void* dtw, const void* dtb, const void* alog,
                       const void* dss, const void* ng, const void* nb, const void* opw,
                       const void* opb, float* wb, const float* flag) {
  bool f = flag[0] > 0.5f;
  int i = blockIdx.x * 256 + threadIdx.x;
  if (i < 9216) {
    int r = i / 96, c = i % 96;
    wb[W_INT + c * 96 + r] = ldu(ipw, i, f);
    wb[W_OUTT + c * 96 + r] = ldu(opw, i, f);
  }
  if (i < 96) {
    wb[B_IN + i] = ldu(ipb, i, f); wb[B_C2D + i] = ldu(c2b, i, f); wb[B_LOC + i] = ldu(lb, i, f);
    wb[BN_G + i] = ldu(bng, i, f); wb[BN_B + i] = ldu(bnb, i, f); wb[LN_G + i] = ldu(ng, i, f);
    wb[LN_B + i] = ldu(nb, i, f); wb[B_OUT + i] = ldu(opb, i, f);
  }
  if (i < 864) { wb[W_C2D + i] = ldu(c2w, i, f); wb[W_LOC + i] = ldu(lw, i, f); }
  if (i < 7296) {
    int k = i / 3648, c = (i / 96) % 38, d = i % 96;
    wb[W_XPT + d * 80 + k * 38 + c] = ldu(xpw, i, f);
  }
  if (i < 1152) wb[W_DT + i] = ldu(dtw, i, f);
  if (i < 192) { wb[B_DT + i] = ldu(dtb, i, f); wb[DSOF + i] = ldu(dss, i, f); }
  if (i < 3072) {
    float av = expf(ldu(alog, i, f));
    wb[A2OF + i] = -av * 1.4426950408889634f;
    wb[W_EC + i] = (float)((i % 16) + 1) - av;
  }
}

// ---------------- in_proj (acc-major, d-split x2, 128 thr) ----------------
__global__ __launch_bounds__(128, 4)
void k_inproj(const void* __restrict__ x, const float* __restrict__ wb,
              float* __restrict__ xfeat, const float* __restrict__ flag) {
  int b = blockIdx.x / 36;
  int rest = blockIdx.x % 36;
  int half = rest / 18;
  int l = (rest % 18) * 128 + threadIdx.x;
  float acc[48];
#pragma unroll
  for (int j = 0; j < 48; ++j) acc[j] = wb[B_IN + half * 48 + j];
  bool f = flag[0] > 0.5f;
  if (f) {
    const float* xf = (const float*)x;
#pragma unroll 2
    for (int c = 0; c < 96; ++c) {
      float xc = xf[(b * 96 + c) * LL + l];
      const float* wr = wb + W_INT + c * 96 + half * 48;
#pragma unroll
      for (int j = 0; j < 48; ++j) acc[j] += xc * wr[j];
    }
  } else {
    const bf16* xb = (const bf16*)x;
#pragma unroll 2
    for (int c = 0; c < 96; ++c) {
      float xc = b2f(xb[(b * 96 + c) * LL + l]);
      const float* wr = wb + W_INT + c * 96 + half * 48;
#pragma unroll
      for (int j = 0; j < 48; ++j) acc[j] += xc * wr[j];
    }
  }
#pragma unroll
  for (int j = 0; j < 48; ++j) xfeat[(b * 96 + half * 48 + j) * LL + l] = acc[j];
}

// ---------------- depthwise 3x3 + bias + silu ----------------
__global__ __launch_bounds__(256, 8)
void k_conv_silu(const float* __restrict__ xfeat, const float* __restrict__ wb,
                 float* __restrict__ xconv) {
  int t = blockIdx.x * 256 + threadIdx.x;
  int l = t % LL; int d = (t / LL) % 96; int b = t / (LL * 96);
  int h = l / 48, w = l % 48;
  const float* wr = wb + W_C2D + d * 9;
  const float* src = xfeat + (b * 96 + d) * LL;
  float acc = wb[B_C2D + d];
#pragma unroll
  for (int ki = 0; ki < 3; ++ki) {
    int hh = h + ki - 1; if (hh < 0 || hh >= 48) continue;
#pragma unroll
    for (int kj = 0; kj < 3; ++kj) {
      int ww = w + kj - 1; if (ww < 0 || ww >= 48) continue;
      acc += src[hh * 48 + ww] * wr[ki * 3 + kj];
    }
  }
  xconv[t] = acc / (1.f + expf(-acc));
}

// ---------------- cosine-sim vs center pixel ----------------
__global__ __launch_bounds__(256, 8)
void k_sim(const float* __restrict__ xconv, float* __restrict__ sim) {
  int b = blockIdx.x / 9;
  int l = (blockIdx.x % 9) * 256 + threadIdx.x;
  const float* base = xconv + (size_t)b * 96 * LL;
  float dot = 0, nrm = 0, cn = 0;
  for (int d = 0; d < 96; ++d) {
    float v = base[d * LL + l];
    float c = base[d * LL + 1176];
    dot += v * c; nrm += v * v; cn += c * c;
  }
  float den = fmaxf(sqrtf(nrm), 1e-12f) * fmaxf(sqrtf(cn), 1e-12f);
  sim[b * LL + l] = dot / den;
}

// ---------------- per-batch stable argsort desc (bitonic) ----------------
__global__ void k_sort(const float* __restrict__ sim, int* __restrict__ sidx) {
  __shared__ unsigned long long key[4096];
  int b = blockIdx.x;
  for (int i = threadIdx.x; i < 4096; i += 1024) {
    unsigned long long kv = ~0ull;
    if (i < LL) {
      unsigned u = __float_as_uint(sim[b * LL + i]);
      u = (u >> 31) ? ~u : (u | 0x80000000u);
      kv = (((unsigned long long)(~u)) << 32) | (unsigned)i;
    }
    key[i] = kv;
  }
  __syncthreads();
  for (int k = 2; k <= 4096; k <<= 1)
    for (int j = k >> 1; j > 0; j >>= 1) {
      for (int i = threadIdx.x; i < 4096; i += 1024) {
        int ij = i ^ j;
        if (ij > i) {
          unsigned long long a = key[i], c = key[ij];
          bool up = ((i & k) == 0);
          if ((a > c) == up) { key[i] = c; key[ij] = a; }
        }
      }
      __syncthreads();
    }
  for (int i = threadIdx.x; i < LL; i += 1024) sidx[b * LL + i] = (int)(key[i] & 0xffffffffu);
}

// ---------------- gather + dual-layout emit: xstd[b][d][l'] and xst[b][l'][d] ----------------
__global__ __launch_bounds__(256, 4)
void k_gather_tr(const float* __restrict__ xconv, const int* __restrict__ sidx,
                 float* __restrict__ xstd, float* __restrict__ xst) {
  __shared__ float tile[64 * 97];
  __shared__ int sp[64];
  int b = blockIdx.x / 36;
  int l0 = (blockIdx.x % 36) * 64;
  if (threadIdx.x < 64) sp[threadIdx.x] = sidx[b * LL + l0 + threadIdx.x];
  __syncthreads();
#pragma unroll
  for (int it = 0; it < 24; ++it) {
    int idx = it * 256 + threadIdx.x;
    int d = idx / 64, j = idx % 64;
    tile[j * 97 + d] = xconv[((size_t)b * 96 + d) * LL + sp[j]];
  }
  __syncthreads();
#pragma unroll
  for (int it = 0; it < 24; ++it) {
    int idx = it * 256 + threadIdx.x;
    int d = idx / 64, j = idx % 64;
    xstd[((size_t)b * 96 + d) * LL + l0 + j] = tile[j * 97 + d];
  }
#pragma unroll
  for (int it = 0; it < 24; ++it) {
    int idx = it * 256 + threadIdx.x;
    int r = idx / 96, c = idx % 96;
    xst[((size_t)b * LL + l0 + r) * 96 + c] = tile[r * 97 + c];
  }
}

// ---------------- x_dbl for one direction (acc-major, 128 thr) ----------------
template <int KSEL>
__global__ __launch_bounds__(128, 4)
void k_xdbl(const float* __restrict__ xstd, const float* __restrict__ wb,
            float* __restrict__ rbuf, float* __restrict__ bc) {
  int b = blockIdx.x / 18;
  int l = (blockIdx.x % 18) * 128 + threadIdx.x;
  float acc[38];
#pragma unroll
  for (int j = 0; j < 38; ++j) acc[j] = 0.f;
#pragma unroll 2
  for (int c = 0; c < 96; ++c) {
    float xc = xstd[((size_t)b * 96 + c) * LL + l];
    const float* wr = wb + W_XPT + c * 80 + KSEL * 38;   // uniform -> s_load
#pragma unroll
    for (int j = 0; j < 38; ++j) acc[j] += xc * wr[j];
  }
  int lout = KSEL ? (LL - 1 - l) : l;
  float4* r4 = (float4*)(rbuf + ((size_t)(b * 2 + KSEL) * LL + lout) * 8);
  r4[0] = make_float4(acc[0], acc[1], acc[2], acc[3]);
  r4[1] = make_float4(acc[4], acc[5], 0.f, 0.f);
  float4* b4 = (float4*)(bc + ((size_t)(b * 2 + KSEL) * LL + lout) * 32);
#pragma unroll
  for (int i = 0; i < 8; ++i)
    b4[i] = make_float4(acc[6 + 4 * i], acc[7 + 4 * i], acc[8 + 4 * i], acc[9 + 4 * i]);
}

// ---------------- scan pass 1: paired segments, LDS-staged bc/rr/xq ----------------
__global__ __launch_bounds__(192, 4)
void k_scan1(const float* __restrict__ rbuf, const float* __restrict__ bc,
             const float* __restrict__ xst, const float* __restrict__ wb,
             float* __restrict__ dsum, float* __restrict__ hend) {
  __shared__ float sbc[2][1024];
  __shared__ float srr[2][256];
  __shared__ float xq[32 * 96];
  int t = threadIdx.x;
  int sub = t / 96;                    // sub==k
  int d = t - sub * 96;
  int k = sub;
  int b = blockIdx.x / NSEG;
  int u = blockIdx.x % NSEG;           // q-window index
  int s = sub ? (NSEG - 1 - u) : u;    // per-direction segment
  int lbase = (b * 2 + k) * LL + s * 32;
  {
    const float4* bsrc = (const float4*)(bc + (size_t)lbase * 32);
    float4* bdst = (float4*)sbc[sub];
    for (int i = d; i < 256; i += 96) bdst[i] = bsrc[i];
    const float4* rsrc = (const float4*)(rbuf + (size_t)lbase * 8);
    float4* rdst = (float4*)srr[sub];
    if (d < 64) rdst[d] = rsrc[d];
    // shared x tile: q in [u*32, u*32+32)
    const float4* xsrc = (const float4*)(xst + ((size_t)b * LL + u * 32) * 96);
    float4* xdst = (float4*)xq;
    for (int i = t; i < 768; i += 192) xdst[i] = xsrc[i];
  }
  __syncthreads();
  float wd[6];
#pragma unroll
  for (int j = 0; j < 6; ++j) wd[j] = wb[W_DT + (k * 96 + d) * 6 + j];
  float bd = wb[B_DT + k * 96 + d];
  float ec[16], h[16];
#pragma unroll
  for (int n = 0; n < 16; ++n) { ec[n] = wb[W_EC + (k * 96 + d) * 16 + n]; h[n] = 0.f; }
  float ds = 0.f;
#pragma unroll 4
  for (int i = 0; i < 32; ++i) {
    int qloc = k ? (31 - i) : i;
    float xv = xq[qloc * 96 + d];
    const float* rr = &srr[sub][i * 8];
    const float* bcl = &sbc[sub][i * 32];
    float a = bd + rr[0] * wd[0] + rr[1] * wd[1] + rr[2] * wd[2]
                 + rr[3] * wd[3] + rr[4] * wd[4] + rr[5] * wd[5];
    float ea = expf(a);
    float dtv = (a > 20.f) ? a : log1pf(ea);
    float dtx = dtv * xv;
    float P = 1.f / (1.f + ea);
    ds += dtv;
    float pwn = 1.f;
#pragma unroll
    for (int n = 0; n < 16; ++n) {
      pwn *= P;
      float tt = ec[n] * dtv;
      float cu = fmaf(tt, 0.16666667f, 0.5f);
      float cv = fmaf(tt, cu, 1.f);
      float corr = fmaf(tt, cv, 1.f);
      h[n] = fmaf(pwn * corr, h[n], dtx * bcl[n]);
    }
  }
  dsum[((b * 2 + k) * 96 + d) * NSEG + s] = ds;
  float4* ho = (float4*)(hend + (((size_t)(b * 2 + k) * NSEG + s) * 96 + d) * 16);
  ho[0] = make_float4(h[0], h[1], h[2], h[3]);
  ho[1] = make_float4(h[4], h[5], h[6], h[7]);
  ho[2] = make_float4(h[8], h[9], h[10], h[11]);
  ho[3] = make_float4(h[12], h[13], h[14], h[15]);
}

// ---------------- scan pass 2: stitch 72 segments ----------------
__global__ __launch_bounds__(256, 4)
void k_scan2(const float* __restrict__ dsum, const float* __restrict__ hend,
             const float* __restrict__ wb, float* __restrict__ hstart) {
  int t = blockIdx.x * 256 + threadIdx.x;
  int n = t % 16; int d = (t / 16) % 96; int k = (t / 1536) % 2; int b = t / 3072;
  float a2 = wb[A2OF + (k * 96 + d) * 16 + n];
  float h = 0.f;
  int rowd = ((b * 2 + k) * 96 + d) * NSEG;
  for (int s = 0; s < NSEG; ++s) {
    size_t idx = (((size_t)(b * 2 + k) * NSEG + s) * 96 + d) * 16 + n;
    hstart[idx] = h;
    h = exp2f(a2 * dsum[rowd + s]) * h + hend[idx];
  }
}

// ---------------- scan3 + combine + LN (single y-tile, LDS atomic add) ----------------
__global__ __launch_bounds__(192, 4)
void k_scan3ln(const float* __restrict__ rbuf, const float* __restrict__ bc,
               const float* __restrict__ xst, const float* __restrict__ wb,
               const float* __restrict__ hstart, const int* __restrict__ sidx,
               float* __restrict__ ymlm) {
  __shared__ float yt[32 * 97];
  __shared__ float sbc[2][1024];
  __shared__ float srr[2][256];
  __shared__ float xq[32 * 96];
  __shared__ float smu[32], srs[32];
  int b = blockIdx.x / NSEG;
  int u = blockIdx.x % NSEG;
  int t = threadIdx.x;
  int sub = t / 96;                      // sub==k
  int d = t - sub * 96;
  int k = sub;
  int seg = sub ? (NSEG - 1 - u) : u;
  int lbase = (b * 2 + k) * LL + seg * 32;
  for (int i = t; i < 32 * 97; i += 192) yt[i] = 0.f;
  {
    const float4* bsrc = (const float4*)(bc + (size_t)lbase * 32);
    float4* bdst = (float4*)sbc[sub];
    for (int i = d; i < 256; i += 96) bdst[i] = bsrc[i];
    const float4* rsrc = (const float4*)(rbuf + (size_t)lbase * 8);
    float4* rdst = (float4*)srr[sub];
    if (d < 64) rdst[d] = rsrc[d];
    const float4* xsrc = (const float4*)(xst + ((size_t)b * LL + u * 32) * 96);
    float4* xdst = (float4*)xq;
    for (int i = t; i < 768; i += 192) xdst[i] = xsrc[i];
  }
  __syncthreads();
  {
    float wd[6];
#pragma unroll
    for (int j = 0; j < 6; ++j) wd[j] = wb[W_DT + (k * 96 + d) * 6 + j];
    float bd = wb[B_DT + k * 96 + d];
    float Dv = wb[DSOF + k * 96 + d];
    float ec[16], h[16];
    const float* hi = hstart + (((size_t)(b * 2 + k) * NSEG + seg) * 96 + d) * 16;
#pragma unroll
    for (int n = 0; n < 16; ++n) { ec[n] = wb[W_EC + (k * 96 + d) * 16 + n]; h[n] = hi[n]; }
#pragma unroll 4
    for (int i = 0; i < 32; ++i) {
      int qloc = k ? (31 - i) : i;
      float xv = xq[qloc * 96 + d];
      const float* rr = &srr[sub][i * 8];
      const float* bcl = &sbc[sub][i * 32];
      float a = bd + rr[0] * wd[0] + rr[1] * wd[1] + rr[2] * wd[2]
                   + rr[3] * wd[3] + rr[4] * wd[4] + rr[5] * wd[5];
      float ea = expf(a);
      float dtv = (a > 20.f) ? a : log1pf(ea);
      float dtx = dtv * xv;
      float P = 1.f / (1.f + ea);
      float pwn = 1.f;
      float y = 0.f;
#pragma unroll
      for (int n = 0; n < 16; ++n) {
        pwn *= P;
        float tt = ec[n] * dtv;
        float cu = fmaf(tt, 0.16666667f, 0.5f);
        float cv = fmaf(tt, cu, 1.f);
        float corr = fmaf(tt, cv, 1.f);
        h[n] = fmaf(pwn * corr, h[n], dtx * bcl[n]);
        y = fmaf(h[n], bcl[16 + n], y);
      }
      atomicAdd(&yt[qloc * 97 + d], y + Dv * xv);
    }
  }
  __syncthreads();
  if (t < 32) {
    float sum = 0, ss = 0;
#pragma unroll
    for (int dd = 0; dd < 96; ++dd) {
      float v = yt[t * 97 + dd];
      sum += v; ss += v * v;
    }
    float mu = sum * (1.f / 96.f);
    float var = ss * (1.f / 96.f) - mu * mu;
    smu[t] = mu;
    srs[t] = rsqrtf(var + 1e-5f);
  }
  __syncthreads();
  {
    int r = t / 6, c0 = (t % 6) * 16;
    int q = u * 32 + r;
    int p = sidx[b * LL + q];
    float mu = smu[r], rs = srs[r];
    float tmp[16];
#pragma unroll
    for (int j = 0; j < 16; ++j) {
      int dd = c0 + j;
      tmp[j] = (yt[r * 97 + dd] - mu) * rs * wb[LN_G + dd] + wb[LN_B + dd];
    }
    float4* o4 = (float4*)(ymlm + ((size_t)b * LL + p) * 96 + c0);
    o4[0] = make_float4(tmp[0], tmp[1], tmp[2], tmp[3]);
    o4[1] = make_float4(tmp[4], tmp[5], tmp[6], tmp[7]);
    o4[2] = make_float4(tmp[8], tmp[9], tmp[10], tmp[11]);
    o4[3] = make_float4(tmp[12], tmp[13], tmp[14], tmp[15]);
  }
}

// ---------------- transpose l-major -> d-major ----------------
__global__ __launch_bounds__(256, 4)
void k_tr_ld(const float* __restrict__ in, float* __restrict__ out) {
  __shared__ float tile[64 * 97];
  int b = blockIdx.x / 36;
  int l0 = (blockIdx.x % 36) * 64;
#pragma unroll
  for (int it = 0; it < 24; ++it) {
    int idx = it * 256 + threadIdx.x;
    int r = idx / 96, c = idx % 96;
    tile[r * 97 + c] = in[((size_t)b * LL + l0 + r) * 96 + c];
  }
  __syncthreads();
#pragma unroll
  for (int it = 0; it < 24; ++it) {
    int idx = it * 256 + threadIdx.x;
    int d = idx / 64, j = idx % 64;
    out[((size_t)b * 96 + d) * LL + l0 + j] = tile[j * 97 + d];
  }
}

// ---------------- local conv + bias + BN stats (fused) ----------------
__global__ __launch_bounds__(256, 8)
void k_convlc_bn(const float* __restrict__ xconv, const float* __restrict__ wb,
                 float* __restrict__ lcbuf, float* __restrict__ stats) {
  int bd = blockIdx.x;
  int b = bd / 96, d = bd % 96;
  const float* src = xconv + (size_t)(b * 96 + d) * LL;
  const float* wr = wb + W_LOC + d * 9;
  float bias = wb[B_LOC + d];
  float s1 = 0, s2 = 0;
  for (int l = threadIdx.x; l < LL; l += 256) {
    int h = l / 48, w = l % 48;
    float acc = bias;
#pragma unroll
    for (int ki = 0; ki < 3; ++ki) {
      int hh = h + ki - 1; if (hh < 0 || hh >= 48) continue;
#pragma unroll
      for (int kj = 0; kj < 3; ++kj) {
        int ww = w + kj - 1; if (ww < 0 || ww >= 48) continue;
        acc += src[hh * 48 + ww] * wr[ki * 3 + kj];
      }
    }
    lcbuf[(size_t)(b * 96 + d) * LL + l] = acc;
    s1 += acc; s2 += acc * acc;
  }
  __shared__ float r1[256], r2[256];
  r1[threadIdx.x] = s1; r2[threadIdx.x] = s2; __syncthreads();
  for (int o = 128; o > 0; o >>= 1) {
    if (threadIdx.x < o) { r1[threadIdx.x] += r1[threadIdx.x + o]; r2[threadIdx.x] += r2[threadIdx.x + o]; }
    __syncthreads();
  }
  if (threadIdx.x == 0) { atomicAdd(&stats[d], r1[0]); atomicAdd(&stats[96 + d], r2[0]); }
}

__global__ void k_bnfin(const float* __restrict__ stats, const float* __restrict__ wb,
                        float* __restrict__ scsh) {
  int d = threadIdx.x; if (d >= 96) return;
  float mean = stats[d] * (1.f / 73728.f);
  float var = stats[96 + d] * (1.f / 73728.f) - mean * mean;
  float sc = wb[BN_G + d] * rsqrtf(var + 1e-5f);
  scsh[d] = sc; scsh[96 + d] = wb[BN_B + d] - mean * sc;
}

// ---------------- final (acc-major, c-split x2, 128 thr) ----------------
__global__ __launch_bounds__(128, 4)
void k_final(const float* __restrict__ lcbuf, const float* __restrict__ ymdm,
             const float* __restrict__ wb, const float* __restrict__ scsh,
             void* __restrict__ out, const float* __restrict__ flag) {
  int b = blockIdx.x / 36;
  int rest = blockIdx.x % 36;
  int half = rest / 18;
  int l = (rest % 18) * 128 + threadIdx.x;
  float acc[48];
#pragma unroll
  for (int j = 0; j < 48; ++j) acc[j] = wb[B_OUT + half * 48 + j];
#pragma unroll 2
  for (int d = 0; d < 96; ++d) {
    float lc = lcbuf[((size_t)b * 96 + d) * LL + l] * scsh[d] + scsh[96 + d];
    float vd = lc / (1.f + expf(-lc)) + ymdm[((size_t)b * 96 + d) * LL + l];
    const float* wr = wb + W_OUTT + d * 96 + half * 48;   // uniform -> s_load
#pragma unroll
    for (int j = 0; j < 48; ++j) acc[j] += vd * wr[j];
  }
  bool f = flag[0] > 0.5f;
  if (f) {
    float* of = (float*)out;
#pragma unroll
    for (int j = 0; j < 48; ++j) of[(b * 96 + half * 48 + j) * LL + l] = acc[j];
  } else {
    bf16* ob = (bf16*)out;
#pragma unroll
    for (int j = 0; j < 48; ++j) ob[(b * 96 + half * 48 + j) * LL + l] = __float2bfloat16(acc[j]);
  }
}

extern "C" void kernel_launch(void* const* d_in, const int* in_sizes, int n_in,
                              void* d_out, int out_size, void* d_ws, size_t ws_size,
                              hipStream_t stream) {
  if (ws_size < O_END * sizeof(float)) return;
  float* ws = (float*)d_ws;
  float* wb    = ws + O_WBUF;
  float* xfeat = ws + O_XFEAT;
  float* xconv = ws + O_XCONV;
  float* sim   = ws + O_SIM;
  int*   sidx  = (int*)(ws + O_SIDX);
  float* xst   = ws + O_XST;
  float* xstd  = ws + O_XSTD;
  float* rbuf  = ws + O_RBUF;
  float* bc    = ws + O_BC;
  float* dsum  = ws + O_DSUM;
  float* ymlm  = ws + O_YMLM;
  float* stats = ws + O_STATS;
  float* scsh  = ws + O_SCSH;
  float* flag  = ws + O_FLAG;
  float* hend   = xfeat;   // xfeat dead after conv_silu
  float* hstart = xstd;    // xstd dead after xdbl
  float* ymdm   = xfeat;   // hend dead after scan2
  float* lcbuf  = xst;     // xst dead after scan3ln

  (void)hipMemsetAsync(stats, 0, 192 * sizeof(float), stream);
  k_detect<<<1, 64, 0, stream>>>(d_in[0], flag);
  k_prep<<<36, 256, 0, stream>>>(
      d_in[1], d_in[2], d_in[5], d_in[6], d_in[7], d_in[8], d_in[9], d_in[10],
      d_in[11], d_in[12], d_in[13], d_in[14], d_in[15], d_in[16], d_in[17], d_in[18],
      d_in[19], wb, flag);
  k_inproj<<<1152, 128, 0, stream>>>(d_in[0], wb, xfeat, flag);
  k_conv_silu<<<27648, 256, 0, stream>>>(xfeat, wb, xconv);
  k_sim<<<288, 256, 0, stream>>>(xconv, sim);
  k_sort<<<32, 1024, 0, stream>>>(sim, sidx);
  k_gather_tr<<<1152, 256, 0, stream>>>(xconv, sidx, xstd, xst);
  k_xdbl<0><<<576, 128, 0, stream>>>(xstd, wb, rbuf, bc);
  k_xdbl<1><<<576, 128, 0, stream>>>(xstd, wb, rbuf, bc);
  k_scan1<<<2304, 192, 0, stream>>>(rbuf, bc, xst, wb, dsum, hend);
  k_scan2<<<384, 256, 0, stream>>>(dsum, hend, wb, hstart);
  k_scan3ln<<<2304, 192, 0, stream>>>(rbuf, bc, xst, wb, hstart, sidx, ymlm);
  k_tr_ld<<<1152, 256, 0, stream>>>(ymlm, ymdm);
  k_convlc_bn<<<3072, 256, 0, stream>>>(xconv, wb, lcbuf, stats);
  k_bnfin<<<1, 96, 0, stream>>>(stats, wb, scsh);
  k_final<<<1152, 128, 0, stream>>>(lcbuf, ymdm, wb, scsh, d_out, flag);
}